// Round 7
// baseline (1388.476 us; speedup 1.0000x reference)
//
#include <hip/hip_runtime.h>

typedef __bf16 bf16_t;
typedef __bf16 bf16x8v __attribute__((ext_vector_type(8)));
typedef float f32x4 __attribute__((ext_vector_type(4)));

#define CB 4
#define CS 1024
#define CE 768
#define CH 12
#define CD 64

// ===== MFMA GEMM, all-bf16 operands, B pre-transposed [N,K], BK=64, reg-prefetch =====
// CONCAT: k-tile < 768 -> A0, >= 768 -> A1 (768 % 64 == 0 so tiles never straddle).
// ACT: 0 none, 1 sigmoid, 2 gelu, 3 sigmoid-blend (C=g*resid_bf16+(1-g)*C2_bf16),
//      4 scale 0.125, 5 gate-t (g=sigm(v); C = g*resid_f32 + (1-g)*C2_bf16).
// RES: 0 none, 2 += f32 resid. OUT: 0 bf16 C, 1 f32 C, 2 f32 C + bf16 C2.
// CMODE: 0 normal(ldc); 2 split [b,H,s,d]; 3 split [b,H,d,s];
//        4 qkv->C,C2,C3; 5 kv: k->C [bb,H,s,d], v->C2 [bb,H,d,s] (bias2 for v).
template<int BM, int BN, int CONCAT, int ACT, int RES, int OUT, int CMODE>
__global__ __launch_bounds__(256)
void gemm_n(const bf16_t* __restrict__ A0, const bf16_t* __restrict__ A1,
            const bf16_t* __restrict__ Bt, const float* __restrict__ bias,
            const float* __restrict__ bias2, const void* __restrict__ resid,
            void* __restrict__ C, void* __restrict__ C2, void* __restrict__ C3,
            int M, int N, int K, int lda, int ldc)
{
    constexpr int WM = BM / 2, WN = BN / 2, RM = WM / 16, RN = WN / 16;
    constexpr int PK = 72;                  // 64 + 8 pad
    constexpr int AR = BM / 32, BR = BN / 32;
    __shared__ bf16_t As[BM * PK];
    __shared__ bf16_t Bs[BN * PK];

    const int t = threadIdx.x;
    // XCD-aware swizzle: blocks b === xcd (mod 8) form a compact m-stripe.
    const int Nb = gridDim.x, Mb = gridDim.y;
    int m_blk, n_blk;
    {
        int b = blockIdx.y * Nb + blockIdx.x;
        if ((Mb & 7) == 0) {
            int xcd = b & 7, g = b >> 3, PM = Mb >> 3;
            m_blk = xcd * PM + (g % PM);
            n_blk = g / PM;
        } else { m_blk = blockIdx.y; n_blk = blockIdx.x; }
    }
    const int m0 = m_blk * BM, n0 = n_blk * BN;

    const int r0 = t >> 3, c0 = (t & 7) * 8;
    const int lane = t & 63, wave = t >> 6;
    const int wm = (wave & 1) * WM, wn = (wave >> 1) * WN;
    const int fr = lane & 15, quad = lane >> 4;

    uint4 ra[AR], rb[BR];
    auto loadA = [&](int kt) {
        const bf16_t* src = (CONCAT && kt >= 768) ? A1 : A0;
        int koff = (CONCAT && kt >= 768) ? kt - 768 : kt;
#pragma unroll
        for (int i = 0; i < AR; i++)
            ra[i] = *(const uint4*)&src[(long)(m0 + r0 + i * 32) * lda + koff + c0];
    };
    auto loadB = [&](int kt) {
#pragma unroll
        for (int i = 0; i < BR; i++)
            rb[i] = *(const uint4*)&Bt[(long)(n0 + r0 + i * 32) * K + kt + c0];
    };

    f32x4 acc[RM][RN];
#pragma unroll
    for (int i = 0; i < RM; i++)
#pragma unroll
        for (int j = 0; j < RN; j++)
#pragma unroll
            for (int p = 0; p < 4; p++) acc[i][j][p] = 0.f;

    loadA(0); loadB(0);
    for (int kt = 0; kt < K; kt += 64) {
#pragma unroll
        for (int i = 0; i < AR; i++) *(uint4*)&As[(r0 + i * 32) * PK + c0] = ra[i];
#pragma unroll
        for (int i = 0; i < BR; i++) *(uint4*)&Bs[(r0 + i * 32) * PK + c0] = rb[i];
        __syncthreads();
        if (kt + 64 < K) { loadA(kt + 64); loadB(kt + 64); }  // overlaps compute

#pragma unroll
        for (int ks = 0; ks < 2; ks++) {
            bf16x8v af[RM], bfr[RN];
#pragma unroll
            for (int i = 0; i < RM; i++)
                af[i] = *(const bf16x8v*)&As[(wm + i * 16 + fr) * PK + quad * 8 + ks * 32];
#pragma unroll
            for (int j = 0; j < RN; j++)
                bfr[j] = *(const bf16x8v*)&Bs[(wn + j * 16 + fr) * PK + quad * 8 + ks * 32];
#pragma unroll
            for (int i = 0; i < RM; i++)
#pragma unroll
                for (int j = 0; j < RN; j++)
                    acc[i][j] = __builtin_amdgcn_mfma_f32_16x16x32_bf16(af[i], bfr[j], acc[i][j], 0, 0, 0);
        }
        __syncthreads();
    }

    const int rq = quad * 4, cn = fr;
#pragma unroll
    for (int i = 0; i < RM; i++)
#pragma unroll
        for (int j = 0; j < RN; j++) {
            int col = n0 + wn + j * 16 + cn;
            int t3 = (CMODE >= 4) ? (col / 768) : 0;
            int cc = col - t3 * 768;
            float bv = 0.f;
            if (CMODE == 5) bv = t3 ? bias2[cc] : bias[cc];
            else if (bias)  bv = bias[col];
#pragma unroll
            for (int p = 0; p < 4; p++) {
                int row = m0 + wm + i * 16 + rq + p;
                float v = acc[i][j][p] + bv;
                if (ACT == 2) {
                    float u = 0.7978845608028654f * (v + 0.044715f * v * v * v);
                    v = 0.5f * v * (1.f + tanhf(u));
                }
                if (ACT == 4) v *= 0.125f;
                if (CMODE == 0) {
                    long idx = (long)row * ldc + col;
                    if (ACT == 1) v = 1.f / (1.f + __expf(-v));
                    if (ACT == 3) {
                        float g = 1.f / (1.f + __expf(-v));
                        float a_ = (float)((const bf16_t*)resid)[idx];
                        float e_ = (float)((const bf16_t*)C2)[idx];
                        ((bf16_t*)C)[idx] = (bf16_t)(g * a_ + (1.f - g) * e_);
                        continue;
                    }
                    if (ACT == 5) {
                        float g = 1.f / (1.f + __expf(-v));
                        float r_ = ((const float*)resid)[idx];
                        float e_ = (float)((const bf16_t*)C2)[idx];
                        ((bf16_t*)C)[idx] = (bf16_t)(g * r_ + (1.f - g) * e_);
                        continue;
                    }
                    if (RES == 2) v += ((const float*)resid)[idx];
                    if (OUT == 0)      ((bf16_t*)C)[idx] = (bf16_t)v;
                    else if (OUT == 1) ((float*)C)[idx] = v;
                    else { ((float*)C)[idx] = v; ((bf16_t*)C2)[idx] = (bf16_t)v; }
                } else {
                    int bb = row >> 10, ss = row & 1023;
                    int hh = cc >> 6, dd = cc & 63;
                    long sidx = (((long)(bb * CH + hh) * 1024) + ss) * 64 + dd;
                    long tidx = (((long)(bb * CH + hh) * 64) + dd) * 1024 + ss;
                    if (CMODE == 2)      ((bf16_t*)C)[sidx] = (bf16_t)v;
                    else if (CMODE == 3) ((bf16_t*)C)[tidx] = (bf16_t)v;
                    else if (CMODE == 5) {
                        if (t3 == 0) ((bf16_t*)C)[sidx]  = (bf16_t)v;
                        else         ((bf16_t*)C2)[tidx] = (bf16_t)v;
                    } else {
                        if (t3 == 0)      ((bf16_t*)C)[sidx]  = (bf16_t)v;
                        else if (t3 == 1) ((bf16_t*)C2)[sidx] = (bf16_t)v;
                        else              ((bf16_t*)C3)[tidx] = (bf16_t)v;
                    }
                }
            }
        }
}

// ===== fused flash attention, D=64, 64-row Q tiles, 64-wide key tiles, prefetch =====
// MODE 0: self (no scale, Sk=1024). MODE 1: enc (q pre-scaled, key mask -> -10000,
// Sk=1024). MODE 2: memory (Sk=128 padded, valid 100).
template<int MODE>
__global__ __launch_bounds__(256)
void flash_attn(const bf16_t* __restrict__ Q, const bf16_t* __restrict__ K,
                const bf16_t* __restrict__ V, const int* __restrict__ mask,
                bf16_t* __restrict__ O)
{
    __shared__ bf16_t Qs[64 * 72];   // wave-private 16-row strips; reused for P
    __shared__ bf16_t Ks[64 * 72];
    __shared__ bf16_t Vs[64 * 72];

    const int t = threadIdx.x;
    const int lane = t & 63, wave = t >> 6;
    const int z = blockIdx.z;
    const int b = z / CH, h = z % CH;
    const int q0 = blockIdx.x * 64;

    const bf16_t* Qb = Q + (long)z * (1024 * 64) + (long)q0 * 64;
    const bf16_t* Kb = (MODE == 2) ? K + (long)h * (128 * 64) : K + (long)z * (1024 * 64);
    const bf16_t* Vb = (MODE == 2) ? V + (long)h * (64 * 128) : V + (long)z * (64 * 1024);
    const int ldv = (MODE == 2) ? 128 : 1024;
    const int NT = (MODE == 2) ? 2 : 16;

    const int r0 = t >> 3, c0 = (t & 7) * 8;
    const int fr = lane & 15, quad = lane >> 4;

    uint4 rk[2], rv[2];
    int mv[4];
    auto loadKV = [&](int kt) {
#pragma unroll
        for (int i = 0; i < 2; i++) {
            rk[i] = *(const uint4*)&Kb[(long)(kt * 64 + r0 + i * 32) * 64 + c0];
            rv[i] = *(const uint4*)&Vb[(long)(r0 + i * 32) * ldv + kt * 64 + c0];
        }
        if (MODE == 1)
#pragma unroll
            for (int j = 0; j < 4; j++)
                mv[j] = mask[(long)b * 1024 + kt * 64 + j * 16 + fr];
    };

    for (int rr = r0; rr < 64; rr += 32)
        *(uint4*)&Qs[rr * 72 + c0] = *(const uint4*)&Qb[(long)rr * 64 + c0];
    __syncthreads();

    bf16x8v qf[2];
#pragma unroll
    for (int ks = 0; ks < 2; ks++)
        qf[ks] = *(const bf16x8v*)&Qs[(wave * 16 + fr) * 72 + quad * 8 + ks * 32];

    bf16_t* Ps = &Qs[wave * 16 * 72];

    f32x4 o[4];
    float mrow[4], lrow[4];
#pragma unroll
    for (int p = 0; p < 4; p++) { mrow[p] = -1e30f; lrow[p] = 0.f; }
#pragma unroll
    for (int j = 0; j < 4; j++)
#pragma unroll
        for (int p = 0; p < 4; p++) o[j][p] = 0.f;

    loadKV(0);
    for (int kt = 0; kt < NT; kt++) {
#pragma unroll
        for (int i = 0; i < 2; i++) {
            *(uint4*)&Ks[(r0 + i * 32) * 72 + c0] = rk[i];
            *(uint4*)&Vs[(r0 + i * 32) * 72 + c0] = rv[i];
        }
        int mvc[4];
        if (MODE == 1) { mvc[0]=mv[0]; mvc[1]=mv[1]; mvc[2]=mv[2]; mvc[3]=mv[3]; }
        __syncthreads();
        if (kt + 1 < NT) loadKV(kt + 1);   // overlaps compute

        f32x4 s[4];
#pragma unroll
        for (int j = 0; j < 4; j++)
#pragma unroll
            for (int p = 0; p < 4; p++) s[j][p] = 0.f;
#pragma unroll
        for (int ks = 0; ks < 2; ks++) {
            bf16x8v bk[4];
#pragma unroll
            for (int j = 0; j < 4; j++)
                bk[j] = *(const bf16x8v*)&Ks[(j * 16 + fr) * 72 + quad * 8 + ks * 32];
#pragma unroll
            for (int j = 0; j < 4; j++)
                s[j] = __builtin_amdgcn_mfma_f32_16x16x32_bf16(qf[ks], bk[j], s[j], 0, 0, 0);
        }
        if (MODE == 1) {
#pragma unroll
            for (int j = 0; j < 4; j++)
#pragma unroll
                for (int p = 0; p < 4; p++)
                    s[j][p] = mvc[j] ? -10000.f : s[j][p];
        }
        if (MODE == 2) {
#pragma unroll
            for (int j = 0; j < 4; j++)
                if (kt * 64 + j * 16 + fr >= 100)
#pragma unroll
                    for (int p = 0; p < 4; p++) s[j][p] = -1e30f;
        }
#pragma unroll
        for (int p = 0; p < 4; p++) {
            float tm = fmaxf(fmaxf(s[0][p], s[1][p]), fmaxf(s[2][p], s[3][p]));
            tm = fmaxf(tm, __shfl_xor(tm, 1, 64));
            tm = fmaxf(tm, __shfl_xor(tm, 2, 64));
            tm = fmaxf(tm, __shfl_xor(tm, 4, 64));
            tm = fmaxf(tm, __shfl_xor(tm, 8, 64));
            float mnew = fmaxf(mrow[p], tm);
            float alpha = __expf(mrow[p] - mnew);
            mrow[p] = mnew;
            float rs = 0.f;
#pragma unroll
            for (int j = 0; j < 4; j++) {
                float e = __expf(s[j][p] - mnew);
                s[j][p] = e;
                rs += e;
            }
            rs += __shfl_xor(rs, 1, 64);
            rs += __shfl_xor(rs, 2, 64);
            rs += __shfl_xor(rs, 4, 64);
            rs += __shfl_xor(rs, 8, 64);
            lrow[p] = lrow[p] * alpha + rs;
#pragma unroll
            for (int j = 0; j < 4; j++) o[j][p] *= alpha;
        }
#pragma unroll
        for (int j = 0; j < 4; j++)
#pragma unroll
            for (int p = 0; p < 4; p++)
                Ps[(quad * 4 + p) * 72 + j * 16 + fr] = (bf16_t)s[j][p];
#pragma unroll
        for (int ks = 0; ks < 2; ks++) {
            bf16x8v af = *(const bf16x8v*)&Ps[fr * 72 + quad * 8 + ks * 32];
            bf16x8v bv[4];
#pragma unroll
            for (int j = 0; j < 4; j++)
                bv[j] = *(const bf16x8v*)&Vs[(j * 16 + fr) * 72 + quad * 8 + ks * 32];
#pragma unroll
            for (int j = 0; j < 4; j++)
                o[j] = __builtin_amdgcn_mfma_f32_16x16x32_bf16(af, bv[j], o[j], 0, 0, 0);
        }
        __syncthreads();
    }
#pragma unroll
    for (int p = 0; p < 4; p++) {
        float inv = 1.f / lrow[p];
        int srow = q0 + wave * 16 + quad * 4 + p;
        long base = ((long)b * 1024 + srow) * 768 + h * 64;
#pragma unroll
        for (int j = 0; j < 4; j++)
            O[base + j * 16 + fr] = (bf16_t)(o[j][p] * inv);
    }
}

// ===== LayerNorm rows of 768 (f32 in, bf16 out) =====
__device__ __forceinline__ void ln_body(const float* in, bf16_t* out,
                                        const float* g, const float* b,
                                        long base, long ob, int t)
{
    __shared__ float red[4];
    float v0 = in[base + t], v1 = in[base + t + 256], v2 = in[base + t + 512];
    float s = v0 + v1 + v2;
    for (int m = 32; m; m >>= 1) s += __shfl_xor(s, m, 64);
    if ((t & 63) == 0) red[t >> 6] = s;
    __syncthreads();
    s = red[0] + red[1] + red[2] + red[3];
    __syncthreads();
    const float mu = s * (1.f / 768.f);
    float d0 = v0 - mu, d1 = v1 - mu, d2 = v2 - mu;
    float q = d0 * d0 + d1 * d1 + d2 * d2;
    for (int m = 32; m; m >>= 1) q += __shfl_xor(q, m, 64);
    if ((t & 63) == 0) red[t >> 6] = q;
    __syncthreads();
    q = red[0] + red[1] + red[2] + red[3];
    const float rstd = rsqrtf(q * (1.f / 768.f) + 1e-5f);
    out[ob + t]       = (bf16_t)(g[t]       * d0 * rstd + b[t]);
    out[ob + t + 256] = (bf16_t)(g[t + 256] * d1 * rstd + b[t + 256]);
    out[ob + t + 512] = (bf16_t)(g[t + 512] * d2 * rstd + b[t + 512]);
}

__global__ __launch_bounds__(256)
void ln_kernel(const float* __restrict__ in, bf16_t* __restrict__ out,
               const float* __restrict__ g, const float* __restrict__ b)
{
    const int r = blockIdx.x;
    ln_body(in, out, g, b, (long)r * CE, (long)r * CE, threadIdx.x);
}

__global__ __launch_bounds__(256)
void ln_enc(const float* __restrict__ encf, bf16_t* __restrict__ out,
            const float* __restrict__ g, const float* __restrict__ b)
{   // out row r = e*4096 + bb*1024 + s  <-  encf[(bb*2+e)*1024 + s]
    const int r = blockIdx.x;
    const int e = r >> 12, rr = r & 4095, bb = rr >> 10, s = rr & 1023;
    ln_body(encf, out, g, b, ((long)(bb * 2 + e) * 1024 + s) * CE, (long)r * CE, threadIdx.x);
}

// ===== elementwise =====
__global__ void combine_t(const bf16_t* __restrict__ t1, const bf16_t* __restrict__ t2,
                          float* __restrict__ rf)
{
    long idx = (long)blockIdx.x * 256 + threadIdx.x;
    rf[idx] = ((float)t1[idx] + (float)t2[idx]) * 0.7071067811865476f;
}

__global__ void zero_out(float* __restrict__ out)
{
    out[blockIdx.x * 256 + threadIdx.x] = 0.f;
}

// ===== batched weight transpose+cast: fp32 [K,N] -> bf16 [N,K], 11 weights =====
struct TArgs {
    const float* src[11];
    bf16_t* dst[11];
    int K[11], N[11], pre[12];
};
__global__ __launch_bounds__(256)
void transpose_all(TArgs a)
{
    __shared__ bf16_t tile[32][33];
    int b = blockIdx.x;
    int w = 0;
    while (w < 10 && b >= a.pre[w + 1]) w++;
    int lb = b - a.pre[w];
    const int Kd = a.K[w], Nd = a.N[w];
    int nbx = Nd >> 5;
    int n0 = (lb % nbx) * 32, k0 = (lb / nbx) * 32;
    const float* src = a.src[w];
    bf16_t* dst = a.dst[w];
    int tx = threadIdx.x & 31, ty = threadIdx.x >> 5;
    for (int i = ty; i < 32; i += 8)
        tile[i][tx] = (bf16_t)src[(long)(k0 + i) * Nd + n0 + tx];
    __syncthreads();
    for (int i = ty; i < 32; i += 8)
        dst[(long)(n0 + i) * Kd + k0 + tx] = tile[tx][i];
}

__global__ void mem_gemm(const float* __restrict__ memf, const float* __restrict__ W,
                         const float* __restrict__ bias, bf16_t* __restrict__ out)
{
    int idx = blockIdx.x * 256 + threadIdx.x;
    int n = idx % 1536, m = idx / 1536;
    float acc = bias[n];
    for (int k = 0; k < 768; k++)
        acc += memf[m * 768 + k] * W[(long)k * 1536 + n];
    out[idx] = (bf16_t)acc;
}

__global__ void repack_mem(const bf16_t* __restrict__ mem, bf16_t* __restrict__ mkt,
                           bf16_t* __restrict__ mvt)
{
    int idx = blockIdx.x * 256 + threadIdx.x;
    int d = idx & 63;
    int slot = (idx >> 6) & 127;
    int h = idx >> 13;
    bf16_t kv = (slot < 100) ? mem[slot * 1536 + h * CD + d] : (bf16_t)0.f;
    bf16_t vv = (slot < 100) ? mem[slot * 1536 + CE + h * CD + d] : (bf16_t)0.f;
    mkt[idx] = kv;
    mvt[((long)h * 64 + d) * 128 + slot] = vv;
}

// ===================================================================================
extern "C" void kernel_launch(void* const* d_in, const int* in_sizes, int n_in,
                              void* d_out, int out_size, void* d_ws, size_t ws_size,
                              hipStream_t stream)
{
    (void)in_sizes; (void)n_in; (void)out_size;
    const float* x        = (const float*)d_in[0];
    const float* encf     = (const float*)d_in[1];
    const int*   maskenc  = (const int*)d_in[2];
    const float* ln1_g    = (const float*)d_in[3];
    const float* ln1_b    = (const float*)d_in[4];
    const float* ln2_g    = (const float*)d_in[5];
    const float* ln2_b    = (const float*)d_in[6];
    const float* c_attn_w = (const float*)d_in[7];
    const float* c_attn_b = (const float*)d_in[8];
    const float* aproj_w  = (const float*)d_in[9];
    const float* aproj_b  = (const float*)d_in[10];
    const float* memf     = (const float*)d_in[11];
    const float* mattn_w  = (const float*)d_in[12];
    const float* mattn_b  = (const float*)d_in[13];
    const float* malpha_w = (const float*)d_in[14];
    const float* malpha_b = (const float*)d_in[15];
    const float* fcq_w    = (const float*)d_in[16];
    const float* fcq_b    = (const float*)d_in[17];
    const float* fck_w    = (const float*)d_in[18];
    const float* fck_b    = (const float*)d_in[19];
    const float* fcv_w    = (const float*)d_in[20];
    const float* fcv_b    = (const float*)d_in[21];
    const float* eproj_w  = (const float*)d_in[22];
    const float* eproj_b  = (const float*)d_in[23];
    const float* fa1_w    = (const float*)d_in[24];
    const float* fa1_b    = (const float*)d_in[25];
    const float* fa2_w    = (const float*)d_in[26];
    const float* fa2_b    = (const float*)d_in[27];
    const float* mfc_w    = (const float*)d_in[28];
    const float* mfc_b    = (const float*)d_in[29];
    const float* mproj_w  = (const float*)d_in[30];
    const float* mproj_b  = (const float*)d_in[31];
    float* dout = (float*)d_out;

    size_t off = 0;
    auto alloc = [&](size_t bytes) -> void* {
        void* p = (char*)d_ws + off;
        off = (off + bytes + 255) & ~(size_t)255;
        return p;
    };
    const size_t SZ = (size_t)4096 * 768 * 2;
    const long SZel = (long)4096 * 768;
    bf16_t* wt_cattn  = (bf16_t*)alloc((size_t)2304 * 768 * 2);
    bf16_t* wt_aproj  = (bf16_t*)alloc((size_t)768 * 768 * 2);
    bf16_t* wt_malpha = (bf16_t*)alloc((size_t)768 * 1536 * 2);
    bf16_t* wt_fcq    = (bf16_t*)alloc((size_t)768 * 768 * 2);
    bf16_t* wt_fck    = (bf16_t*)alloc((size_t)768 * 768 * 2);   // wt_fck..wt_fcv
    bf16_t* wt_fcv    = (bf16_t*)alloc((size_t)768 * 768 * 2);   // contiguous [1536,768]
    bf16_t* wt_eproj  = (bf16_t*)alloc((size_t)768 * 768 * 2);
    bf16_t* wt_fa1    = (bf16_t*)alloc((size_t)768 * 1536 * 2);
    bf16_t* wt_fa2    = (bf16_t*)alloc((size_t)768 * 1536 * 2);
    bf16_t* wt_mfc    = (bf16_t*)alloc((size_t)3072 * 768 * 2);
    bf16_t* wt_mproj  = (bf16_t*)alloc((size_t)768 * 3072 * 2);
    bf16_t* membuf = (bf16_t*)alloc((size_t)100 * 1536 * 2);
    bf16_t* mkt    = (bf16_t*)alloc((size_t)CH * 128 * 64 * 2);
    bf16_t* mvt    = (bf16_t*)alloc((size_t)CH * 64 * 128 * 2);
    bf16_t* bufA   = (bf16_t*)alloc(SZ);        // LN out / blended attn
    bf16_t* qbuf   = (bf16_t*)alloc(SZ);        // q [4,12,1024,64]
    bf16_t* kbuf   = (bf16_t*)alloc(2 * SZ);    // k (stacked enc) / gate-t / mid lo
    bf16_t* vtbuf  = (bf16_t*)alloc(2 * SZ);    // v (stacked enc) / mid hi
    bf16_t* asbuf  = (bf16_t*)alloc(2 * SZ);    // attn out: self+mem / enc e0,e1
    bf16_t* bufB   = (bf16_t*)alloc(2 * SZ);    // enc LN [8192,768] / eproj out
    bf16_t* residb = (bf16_t*)alloc(SZ);        // bf16 copy of resid
    float*  residf = (float*)alloc((size_t)4096 * 768 * 4);

    if (off > ws_size) {   // finite diagnostic
        zero_out<<<12288, 256, 0, stream>>>(dout);
        return;
    }
    bf16_t* mid = kbuf;          // [4096,3072] spans kbuf+vtbuf (dead at MLP)
    bf16_t* galbuf = kbuf;       // gate-t terms [2][4096,768] (dead k)
    bf16_t* eobuf = bufB;        // stacked eproj outputs [8192,768]

    const dim3 blk(256);

    // ---- batched weight transposes ----
    {
        TArgs ta;
        const float* srcs[11] = {c_attn_w, aproj_w, malpha_w, fcq_w, fck_w, fcv_w,
                                 eproj_w, fa1_w, fa2_w, mfc_w, mproj_w};
        bf16_t* dsts[11] = {wt_cattn, wt_aproj, wt_malpha, wt_fcq, wt_fck, wt_fcv,
                            wt_eproj, wt_fa1, wt_fa2, wt_mfc, wt_mproj};
        int Ks[11] = {768, 768, 1536, 768, 768, 768, 768, 1536, 1536, 768, 3072};
        int Ns[11] = {2304, 768, 768, 768, 768, 768, 768, 768, 768, 3072, 768};
        int acc0 = 0;
        for (int i = 0; i < 11; i++) {
            ta.src[i] = srcs[i]; ta.dst[i] = dsts[i]; ta.K[i] = Ks[i]; ta.N[i] = Ns[i];
            ta.pre[i] = acc0;
            acc0 += (Ns[i] / 32) * (Ks[i] / 32);
        }
        ta.pre[11] = acc0;
        transpose_all<<<acc0, blk, 0, stream>>>(ta);
    }

    mem_gemm<<<600, blk, 0, stream>>>(memf, mattn_w, mattn_b, membuf);
    repack_mem<<<384, blk, 0, stream>>>(membuf, mkt, mvt);

    // h = LN1(x); qkv with fused head split
    ln_kernel<<<4096, blk, 0, stream>>>(x, bufA, ln1_g, ln1_b);
    gemm_n<128,128,0,0,0,0,4><<<dim3(18, 32), blk, 0, stream>>>(
        bufA, nullptr, wt_cattn, c_attn_b, nullptr, nullptr, qbuf, kbuf, vtbuf,
        4096, 2304, 768, 768, 0);

    // self + memory attention
    flash_attn<0><<<dim3(16, 1, 48), blk, 0, stream>>>(qbuf, kbuf, vtbuf, nullptr, asbuf);
    flash_attn<2><<<dim3(16, 1, 48), blk, 0, stream>>>(qbuf, mkt, mvt, nullptr, asbuf + SZel);

    // memory gate GEMM with fused sigmoid-blend -> bufA (blended attn)
    gemm_n<64,64,1,3,0,0,0><<<dim3(12, 64), blk, 0, stream>>>(
        asbuf, asbuf + SZel, wt_malpha, malpha_b, nullptr, asbuf,
        bufA, asbuf + SZel, nullptr, 4096, 768, 1536, 768, 768);
    // attn proj + residual(x); dual write f32 + bf16
    gemm_n<64,64,0,0,2,2,0><<<dim3(12, 64), blk, 0, stream>>>(
        bufA, nullptr, wt_aproj, aproj_b, nullptr, x, residf, residb, nullptr,
        4096, 768, 768, 768, 768);

    // cross attention: q once (pre-scaled 1/8); both encoders stacked
    ln_kernel<<<4096, blk, 0, stream>>>(residf, bufA, ln1_g, ln1_b);
    gemm_n<64,64,0,4,0,0,2><<<dim3(12, 64), blk, 0, stream>>>(
        bufA, nullptr, wt_fcq, fcq_b, nullptr, nullptr, qbuf, nullptr, nullptr,
        4096, 768, 768, 768, 0);

    ln_enc<<<8192, blk, 0, stream>>>(encf, bufB, ln1_g, ln1_b);
    gemm_n<64,128,0,0,0,0,5><<<dim3(12, 128), blk, 0, stream>>>(
        bufB, nullptr, wt_fck, fck_b, fcv_b, nullptr, kbuf, vtbuf, nullptr,
        8192, 1536, 768, 768, 0);
    flash_attn<1><<<dim3(16, 1, 48), blk, 0, stream>>>(
        qbuf, kbuf, vtbuf, maskenc, asbuf);
    flash_attn<1><<<dim3(16, 1, 48), blk, 0, stream>>>(
        qbuf, kbuf + SZel, vtbuf + SZel, maskenc, asbuf + SZel);
    gemm_n<64,64,0,0,0,0,0><<<dim3(12, 128), blk, 0, stream>>>(
        asbuf, nullptr, wt_eproj, eproj_b, nullptr, nullptr, eobuf, nullptr, nullptr,
        8192, 768, 768, 768, 768);
    // gate GEMMs with fused t = g*a + (1-g)*e
    gemm_n<64,64,1,5,0,0,0><<<dim3(12, 64), blk, 0, stream>>>(
        residb, eobuf, wt_fa1, fa1_b, nullptr, residf,
        galbuf, eobuf, nullptr, 4096, 768, 1536, 768, 768);
    gemm_n<64,64,1,5,0,0,0><<<dim3(12, 64), blk, 0, stream>>>(
        residb, eobuf + SZel, wt_fa2, fa2_b, nullptr, residf,
        galbuf + SZel, eobuf + SZel, nullptr, 4096, 768, 1536, 768, 768);
    combine_t<<<12288, blk, 0, stream>>>(galbuf, galbuf + SZel, residf);

    // MLP
    ln_kernel<<<4096, blk, 0, stream>>>(residf, bufA, ln2_g, ln2_b);
    gemm_n<128,128,0,2,0,0,0><<<dim3(24, 32), blk, 0, stream>>>(
        bufA, nullptr, wt_mfc, mfc_b, nullptr, nullptr, mid, nullptr, nullptr,
        4096, 3072, 768, 768, 3072);
    gemm_n<64,64,0,0,2,1,0><<<dim3(12, 64), blk, 0, stream>>>(
        mid, nullptr, wt_mproj, mproj_b, nullptr, residf, dout, nullptr, nullptr,
        4096, 768, 3072, 3072, 768);
}